// Round 15
// baseline (123.133 us; speedup 1.0000x reference)
//
#include <hip/hip_runtime.h>
#include <hip/hip_bf16.h>

// Problem constants (Qwen3.5-VL vision attention)
constexpr int N_TOK  = 2048;
constexpr int DIM    = 1280;
constexpr int NHEAD  = 16;
constexpr int HD     = 80;
constexpr int QKV_N  = 3 * DIM;   // 3840

using bf16 = __hip_bfloat16;
typedef __attribute__((ext_vector_type(4)))  float f32x4;
typedef __attribute__((ext_vector_type(16))) float f32x16;
typedef __attribute__((ext_vector_type(8)))  short short8;  // 8 bf16 = 4 VGPR
typedef unsigned int uint;

__device__ __forceinline__ float b2f(bf16 x) { return __bfloat162float(x); }
__device__ __forceinline__ bf16  f2b(float x) { return __float2bfloat16(x); }

// pack two floats -> one u32 of 2 bf16 (lo = first)
__device__ __forceinline__ uint pk2(float a, float b) {
  __align__(4) bf16 t[2] = {f2b(a), f2b(b)};
  return *reinterpret_cast<uint*>(t);
}

// async global->LDS, 16B per lane; dest is wave-uniform base + lane*16
typedef const __attribute__((address_space(1))) unsigned int* gas_u32;
typedef __attribute__((address_space(3))) unsigned int* las_u32;
__device__ __forceinline__ void gload_lds16(const void* g, void* l) {
  __builtin_amdgcn_global_load_lds((gas_u32)g, (las_u32)l, 16, 0, 0);
}

// ---------------------------------------------------------------------------
// Fused prep: z=0 cast hs->bf16, z=1 transpose Wqkv, z=2 transpose Wproj.
// ---------------------------------------------------------------------------
__device__ __forceinline__ void transpose_body(const float* __restrict__ W,
                                               bf16* __restrict__ WT, int K, int N) {
  __shared__ float tile[32][33];
  const int n0 = blockIdx.x * 32, k0 = blockIdx.y * 32;
  const int tc = threadIdx.x & 31, tr = threadIdx.x >> 5;
#pragma unroll
  for (int r = tr; r < 32; r += 8)
    tile[r][tc] = W[(size_t)(k0 + r) * N + n0 + tc];
  __syncthreads();
#pragma unroll
  for (int r = tr; r < 32; r += 8)
    WT[(size_t)(n0 + r) * K + k0 + tc] = f2b(tile[tc][r]);
}

__global__ __launch_bounds__(256)
void prep_kernel(const float* __restrict__ hs, bf16* __restrict__ hsb,
                 const float* __restrict__ Wqkv, bf16* __restrict__ WqkvT,
                 const float* __restrict__ Wproj, bf16* __restrict__ WprojT) {
  if (blockIdx.z == 0) {
    const int bid = blockIdx.y * gridDim.x + blockIdx.x;
    if (bid >= (N_TOK * DIM) / 2048) return;
    const int i = bid * 2048 + threadIdx.x * 8;
    const float4 a = *reinterpret_cast<const float4*>(hs + i);
    const float4 b = *reinterpret_cast<const float4*>(hs + i + 4);
    __align__(16) bf16 w[8] = {f2b(a.x), f2b(a.y), f2b(a.z), f2b(a.w),
                               f2b(b.x), f2b(b.y), f2b(b.z), f2b(b.w)};
    *reinterpret_cast<short8*>(hsb + i) = *reinterpret_cast<const short8*>(w);
  } else if (blockIdx.z == 1) {
    transpose_body(Wqkv, WqkvT, DIM, QKV_N);           // grid (120,40)
  } else {
    if (blockIdx.x >= DIM / 32) return;
    transpose_body(Wproj, WprojT, DIM, DIM);           // (40,40)
  }
}

// ---------------------------------------------------------------------------
// m97-style MFMA GEMM (R7-verified): C = A(bf16) @ BT(bf16) + bias(fp32)
// BM=BN=128, BK=64, 4 waves, global_load_lds w16 + pre-swizzled source.
// ---------------------------------------------------------------------------
template <int OBF>  // 1: C bf16, 0: C fp32
__global__ __launch_bounds__(256)
void mfma_gemm(const bf16* __restrict__ A, const bf16* __restrict__ BT,
               const float* __restrict__ bias, void* __restrict__ C,
               int M, int N, int K) {
  __shared__ bf16 As[128 * 64];
  __shared__ bf16 Bs[128 * 64];
  const int tid = threadIdx.x;
  const int wid = tid >> 6, lane = tid & 63;
  const int lm = lane & 15, kg = lane >> 4;
  const int wm = (wid >> 1) * 64, wn = (wid & 1) * 64;
  const int m0 = blockIdx.y * 128, n0 = blockIdx.x * 128;

  const int srow = lane >> 3;
  const int sblk = (lane & 7) ^ srow;

  f32x4 acc[4][4];
#pragma unroll
  for (int i = 0; i < 4; ++i)
#pragma unroll
    for (int j = 0; j < 4; ++j) acc[i][j] = (f32x4){0.f, 0.f, 0.f, 0.f};

  for (int k0 = 0; k0 < K; k0 += 64) {
#pragma unroll
    for (int i = 0; i < 4; ++i) {
      const int slot = i * 4 + wid;
      const int row = slot * 8 + srow;
      gload_lds16(A + (size_t)(m0 + row) * K + k0 + sblk * 8, &As[slot * 512]);
      gload_lds16(BT + (size_t)(n0 + row) * K + k0 + sblk * 8, &Bs[slot * 512]);
    }
    __syncthreads();

#pragma unroll
    for (int kh = 0; kh < 2; ++kh) {
      short8 af[4], bfr[4];
#pragma unroll
      for (int t = 0; t < 4; ++t) {
        const int ar = wm + t * 16 + lm;
        af[t] = *reinterpret_cast<const short8*>(
            &As[ar * 64 + ((kh * 4 + kg) ^ (ar & 7)) * 8]);
        const int br = wn + t * 16 + lm;
        bfr[t] = *reinterpret_cast<const short8*>(
            &Bs[br * 64 + ((kh * 4 + kg) ^ (br & 7)) * 8]);
      }
#pragma unroll
      for (int mi = 0; mi < 4; ++mi)
#pragma unroll
        for (int ni = 0; ni < 4; ++ni)
          acc[mi][ni] = __builtin_amdgcn_mfma_f32_16x16x32_bf16(
              af[mi], bfr[ni], acc[mi][ni], 0, 0, 0);
    }
    __syncthreads();
  }

#pragma unroll
  for (int mi = 0; mi < 4; ++mi) {
#pragma unroll
    for (int ni = 0; ni < 4; ++ni) {
      const int col = n0 + wn + ni * 16 + lm;
      const float bv = bias[col];
#pragma unroll
      for (int r = 0; r < 4; ++r) {
        const int row = m0 + wm + mi * 16 + kg * 4 + r;
        const float v = acc[mi][ni][r] + bv;
        if constexpr (OBF)
          ((bf16*)C)[(size_t)row * N + col] = f2b(v);
        else
          ((float*)C)[(size_t)row * N + col] = v;
      }
    }
  }
}

// ---------------------------------------------------------------------------
// MFMA flash attention, R15: RoPE FUSED (rope kernel deleted).
//  - K-rope computed in-register at issueK (pair-unit staging: thread holds
//    K[r][d] and K[r][d+40] + cos/sin, commits roped fragments).
//  - Q-rope in-register once per block: rotate partner of frag (ck,half) is
//    at lane+-32 with a register-local ck remap -> 5 permlane32_swap/dword.
//  - otherwise identical to R14: 4 waves x 32q, 32x32x16 MFMA, in-register P
//    via permlane, dbuf K + dbuf Vt, ONE barrier/chunk, lazy softmax, XCD remap.
// ---------------------------------------------------------------------------
constexpr int KC   = 64;   // keys per chunk
constexpr int KSTR = 104;  // 208B rows (pads 80..103 never read by 32x32 path)
constexpr int VSTR = 88;   // 176B rows; key XOR swizzle, 16B-aligned reads
constexpr int VROWS = 96;  // 80 real d + 16 zero rows for the dt=2 tile

__global__ __launch_bounds__(256)
void attn_mfma_kernel(const bf16* __restrict__ qkv, const int* __restrict__ cu,
                      const float* __restrict__ cosb, const float* __restrict__ sinb,
                      bf16* __restrict__ out, int nseg) {
  __shared__ bf16 Ks[2][KC * KSTR];      // 26624 B [key][d] (roped)
  __shared__ bf16 Vt[2][VROWS * VSTR];   // 33792 B [d][key^swz], rows 80+ = 0

  // XCD-aware remap (bijective: gridDim.x % 8 == 0)
  const int p = blockIdx.x;
  const int lidx = (p & 7) * (gridDim.x >> 3) + (p >> 3);
  const int xt  = lidx & 15;             // q-tile (N_TOK/128 = 16)
  const int seg = (lidx >> 4) % nseg;
  const int h   = (lidx >> 4) / nseg;

  const int s0 = cu[seg], s1 = cu[seg + 1];
  if (s0 + xt * 128 >= s1) return;  // uniform early-exit

  const int tid  = threadIdx.x;
  const int wid  = tid >> 6, lane = tid & 63;
  const int l31  = lane & 31;
  const int half = lane >> 5;            // 0/1: which 32-lane half
  const float scale = 0.11180339887498949f;  // 80^-0.5

  const int qrow = s0 + xt * 128 + wid * 32 + l31;

  // zero-fill Vt rows 80..95 in BOTH buffers (2 x 176 slots)
#pragma unroll
  for (int t = 0; t < 2; ++t) {
    const int s = tid + t * 256;
    if (s < 352) {
      const int b = s / 176, rem = s % 176;
      const int r = 80 + rem / 11, sl = rem % 11;
      *reinterpret_cast<short8*>(&Vt[b][r * VSTR + sl * 8]) =
          (short8){0, 0, 0, 0, 0, 0, 0, 0};
    }
  }

  // ---- Q load (raw) + in-register RoPE ----
  // qraw[j] = Q[q=l31][d = j*16 + half*8 .. +7]; rotate partner of (j,half)
  // lives at lane+-32 in a different j — assembled via permlane32_swap.
  short8 qraw[5];
  const int nclamp = min(qrow, s1 - 1);
#pragma unroll
  for (int j = 0; j < 5; ++j) {
    const int dbase = j * 16 + half * 8;
    qraw[j] = (qrow < s1)
        ? *reinterpret_cast<const short8*>(qkv + (size_t)qrow * QKV_N + h * HD + dbase)
        : (short8){0, 0, 0, 0, 0, 0, 0, 0};
  }
  short8 part[5];
#pragma unroll
  for (int w = 0; w < 4; ++w) {
    const uint d0 = reinterpret_cast<const uint*>(&qraw[0])[w];
    const uint d1 = reinterpret_cast<const uint*>(&qraw[1])[w];
    const uint d2 = reinterpret_cast<const uint*>(&qraw[2])[w];
    const uint d3 = reinterpret_cast<const uint*>(&qraw[3])[w];
    const uint d4 = reinterpret_cast<const uint*>(&qraw[4])[w];
    auto s1p = __builtin_amdgcn_permlane32_swap(d2, d0, false, false);
    auto s2p = __builtin_amdgcn_permlane32_swap(d4, d2, false, false);
    auto s3p = __builtin_amdgcn_permlane32_swap(d0, d3, false, false);
    auto s4p = __builtin_amdgcn_permlane32_swap(d3, d1, false, false);
    auto s5p = __builtin_amdgcn_permlane32_swap(d1, d4, false, false);
    reinterpret_cast<uint*>(&part[0])[w] = half ? s3p[0] : s1p[1];
    reinterpret_cast<uint*>(&part[1])[w] = half ? s5p[0] : s4p[1];
    reinterpret_cast<uint*>(&part[2])[w] = half ? s1p[0] : s2p[1];
    reinterpret_cast<uint*>(&part[3])[w] = half ? s4p[0] : s3p[1];
    reinterpret_cast<uint*>(&part[4])[w] = half ? s2p[0] : s5p[1];
  }
  short8 qa[5];
  {
    const float* cq = cosb + nclamp * HD;
    const float* sq = sinb + nclamp * HD;
#pragma unroll
    for (int j = 0; j < 5; ++j) {
      const int dbase = j * 16 + half * 8;
      float cv[8], sv[8];
      *reinterpret_cast<float4*>(&cv[0]) = *reinterpret_cast<const float4*>(cq + dbase);
      *reinterpret_cast<float4*>(&cv[4]) = *reinterpret_cast<const float4*>(cq + dbase + 4);
      *reinterpret_cast<float4*>(&sv[0]) = *reinterpret_cast<const float4*>(sq + dbase);
      *reinterpret_cast<float4*>(&sv[4]) = *reinterpret_cast<const float4*>(sq + dbase + 4);
      const float sgn = (dbase < 40) ? -1.f : 1.f;
      __align__(16) bf16 o[8];
#pragma unroll
      for (int e = 0; e < 8; ++e) {
        const float x  = b2f(reinterpret_cast<const bf16*>(&qraw[j])[e]);
        const float xp = b2f(reinterpret_cast<const bf16*>(&part[j])[e]);
        o[e] = f2b(x * cv[e] + sgn * xp * sv[e]);
      }
      qa[j] = *reinterpret_cast<const short8*>(o);
    }
  }

  // ---- staging lambdas ----
  // K: 320 pair-units (row r, slot sl0<5): thread loads K[r][sl0*8..] and
  // K[r][sl0*8+40..] + cos/sin, ropes in-register; commit writes both b128.
  short8 kq1[2], kq2[2];
  short8 vreg[4];
  const int vgrp = tid / 10, vsl = tid % 10;  // valid for tid<160
  auto issueK = [&](int c) {
    const int k0 = s0 + c * KC;
#pragma unroll
    for (int t = 0; t < 2; ++t) {
      const int s = tid + t * 256;
      if (s < 320) {
        const int r = s / 5, sl0 = s % 5;
        const int rr = min(k0 + r, s1 - 1);
        const bf16* kp = qkv + (size_t)rr * QKV_N + DIM + h * HD;
        const short8 x1 = *reinterpret_cast<const short8*>(kp + sl0 * 8);
        const short8 x2 = *reinterpret_cast<const short8*>(kp + 40 + sl0 * 8);
        const float* cp = cosb + rr * HD;
        const float* sp = sinb + rr * HD;
        float c1[8], c2[8], z1[8], z2[8];
        *reinterpret_cast<float4*>(&c1[0]) = *reinterpret_cast<const float4*>(cp + sl0 * 8);
        *reinterpret_cast<float4*>(&c1[4]) = *reinterpret_cast<const float4*>(cp + sl0 * 8 + 4);
        *reinterpret_cast<float4*>(&c2[0]) = *reinterpret_cast<const float4*>(cp + 40 + sl0 * 8);
        *reinterpret_cast<float4*>(&c2[4]) = *reinterpret_cast<const float4*>(cp + 44 + sl0 * 8);
        *reinterpret_cast<float4*>(&z1[0]) = *reinterpret_cast<const float4*>(sp + sl0 * 8);
        *reinterpret_cast<float4*>(&z1[4]) = *reinterpret_cast<const float4*>(sp + sl0 * 8 + 4);
        *reinterpret_cast<float4*>(&z2[0]) = *reinterpret_cast<const float4*>(sp + 40 + sl0 * 8);
        *reinterpret_cast<float4*>(&z2[4]) = *reinterpret_cast<const float4*>(sp + 44 + sl0 * 8);
        __align__(16) bf16 y1[8], y2[8];
#pragma unroll
        for (int e = 0; e < 8; ++e) {
          const float f1 = b2f(reinterpret_cast<const bf16*>(&x1)[e]);
          const float f2v = b2f(reinterpret_cast<const bf16*>(&x2)[e]);
          y1[e] = f2b(f1 * c1[e] - f2v * z1[e]);
          y2[e] = f2b(f2v * c2[e] + f1 * z2[e]);
        }
        kq1[t] = *reinterpret_cast<const short8*>(y1);
        kq2[t] = *reinterpret_cast<const short8*>(y2);
      }
    }
  };
  auto commitK = [&](int buf) {
#pragma unroll
    for (int t = 0; t < 2; ++t) {
      const int s = tid + t * 256;
      if (s < 320) {
        const int r = s / 5, sl0 = s % 5;
        *reinterpret_cast<short8*>(&Ks[buf][r * KSTR + sl0 * 8]) = kq1[t];
        *reinterpret_cast<short8*>(&Ks[buf][r * KSTR + 40 + sl0 * 8]) = kq2[t];
      }
    }
  };
  auto issueV = [&](int c) {
    if (tid < 160) {
      const int k0 = s0 + c * KC;
#pragma unroll
      for (int e = 0; e < 4; ++e) {
        const int r = min(k0 + vgrp * 4 + e, s1 - 1);
        vreg[e] = *reinterpret_cast<const short8*>(
            qkv + (size_t)r * QKV_N + 2 * DIM + h * HD + vsl * 8);
      }
    }
  };
  auto commitV = [&](int buf) {
    if (tid < 160) {
      const int r0 = vgrp * 4;
      const int swz = (vsl & 7) << 3;
#pragma unroll
      for (int de = 0; de < 8; ++de) {
        __align__(8) bf16 w[4] = {reinterpret_cast<const bf16*>(&vreg[0])[de],
                                  reinterpret_cast<const bf16*>(&vreg[1])[de],
                                  reinterpret_cast<const bf16*>(&vreg[2])[de],
                                  reinterpret_cast<const bf16*>(&vreg[3])[de]};
        *reinterpret_cast<uint2*>(&Vt[buf][(vsl * 8 + de) * VSTR + (r0 ^ swz)]) =
            *reinterpret_cast<const uint2*>(w);
      }
    }
  };

  f32x16 oacc[3];
#pragma unroll
  for (int dt = 0; dt < 3; ++dt)
#pragma unroll
    for (int r = 0; r < 16; ++r) oacc[dt][r] = 0.f;
  float m = -1e30f, l = 0.f;   // per-lane; q's data lives in lanes q, q+32
  const int nch = (s1 - s0 + KC - 1) / KC;

  issueK(0);
  issueV(0);
  commitK(0);
  commitV(0);
  if (nch > 1) {
    issueK(1);
    issueV(1);
  }
  __syncthreads();

  for (int c = 0; c < nch; ++c) {
    const int cur = c & 1;
    const int nk = min(KC, s1 - (s0 + c * KC));

    // 1. S^T = K . Q^T : 2 key-tiles x 5 d-chunks (32x32x16)
    f32x16 sc[2];
    __builtin_amdgcn_s_setprio(1);
#pragma unroll
    for (int kt = 0; kt < 2; ++kt) {
#pragma unroll
      for (int r = 0; r < 16; ++r) sc[kt][r] = 0.f;
#pragma unroll
      for (int ck = 0; ck < 5; ++ck) {
        short8 ka = *reinterpret_cast<const short8*>(
            &Ks[cur][(kt * 32 + l31) * KSTR + ck * 16 + half * 8]);
        sc[kt] = __builtin_amdgcn_mfma_f32_32x32x16_bf16(ka, qa[ck], sc[kt], 0, 0, 0);
      }
    }
    __builtin_amdgcn_s_setprio(0);

    // 2. pipeline: commit K/V(c+1) into buf^1, issue K/V(c+2)
    if (c + 1 < nch) {
      commitK(cur ^ 1);
      commitV(cur ^ 1);
    }
    if (c + 2 < nch) {
      issueK(c + 2);
      issueV(c + 2);
    }

    // 3. scale, tail-mask, LAZY online softmax
#pragma unroll
    for (int kt = 0; kt < 2; ++kt)
#pragma unroll
      for (int r = 0; r < 16; ++r) sc[kt][r] *= scale;
    if (nk < KC) {
#pragma unroll
      for (int kt = 0; kt < 2; ++kt)
#pragma unroll
        for (int r = 0; r < 16; ++r) {
          const int key = kt * 32 + (r & 3) + 8 * (r >> 2) + 4 * half;
          if (key >= nk) sc[kt][r] = -1e30f;
        }
    }
    float rml = sc[0][0];
#pragma unroll
    for (int kt = 0; kt < 2; ++kt)
#pragma unroll
      for (int r = 0; r < 16; ++r)
        if (kt | r) rml = fmaxf(rml, sc[kt][r]);
    if (!__all(rml - m <= 8.0f)) {   // rare: real max growth -> full reduce
      float rm = fmaxf(rml, __shfl_xor(rml, 32));
      const float mnew = fmaxf(m, rm);
      const float fs = __expf(m - mnew);
      m = mnew;
      l *= fs;
#pragma unroll
      for (int dt = 0; dt < 3; ++dt)
#pragma unroll
        for (int r = 0; r < 16; ++r) oacc[dt][r] *= fs;
    }
    // exp in place; per-lane partial l (P bounded by e^8)
#pragma unroll
    for (int kt = 0; kt < 2; ++kt)
#pragma unroll
      for (int r = 0; r < 16; ++r) {
        sc[kt][r] = __expf(sc[kt][r] - m);
        l += sc[kt][r];
      }

    // 4. P -> bf16 words -> permlane32_swap assembly of PV B-frags.
    uint pbw[4][4];  // [kchunk = kt*2+kc2][word 0..3]
#pragma unroll
    for (int kt = 0; kt < 2; ++kt) {
      uint w[8];
#pragma unroll
      for (int i = 0; i < 8; ++i) w[i] = pk2(sc[kt][2 * i], sc[kt][2 * i + 1]);
#pragma unroll
      for (int kc2 = 0; kc2 < 2; ++kc2) {
        auto r02 = __builtin_amdgcn_permlane32_swap(w[4 * kc2 + 0],
                                                    w[4 * kc2 + 2], false, false);
        auto r13 = __builtin_amdgcn_permlane32_swap(w[4 * kc2 + 1],
                                                    w[4 * kc2 + 3], false, false);
        pbw[kt * 2 + kc2][0] = r02[0];
        pbw[kt * 2 + kc2][1] = r13[0];
        pbw[kt * 2 + kc2][2] = r02[1];
        pbw[kt * 2 + kc2][3] = r13[1];
      }
    }

    // 5. O^T += V^T . P^T : 4 key-chunks x 3 d-tiles (32x32x16)
    __builtin_amdgcn_s_setprio(1);
#pragma unroll
    for (int kc = 0; kc < 4; ++kc) {
      short8 pb = *reinterpret_cast<const short8*>(&pbw[kc][0]);
#pragma unroll
      for (int dt = 0; dt < 3; ++dt) {
        const int d = dt * 32 + l31;
        short8 va = *reinterpret_cast<const short8*>(
            &Vt[cur][d * VSTR + ((kc * 16 + half * 8) ^ (((d >> 3) & 7) << 3))]);
        oacc[dt] = __builtin_amdgcn_mfma_f32_32x32x16_bf16(va, pb, oacc[dt], 0, 0, 0);
      }
    }
    __builtin_amdgcn_s_setprio(0);

    __syncthreads();  // single barrier: seals buf^1 writes, frees buf[cur]
  }

  // ---- epilogue: l across halves; D row = (reg&3)+8*(reg>>2)+4*half ----
  l += __shfl_xor(l, 32);
  if (qrow < s1) {
    const float inv = 1.f / l;
    bf16* op = out + (size_t)qrow * DIM + h * HD;
#pragma unroll
    for (int dt = 0; dt < 3; ++dt) {
#pragma unroll
      for (int g = 0; g < 4; ++g) {
        const int d = dt * 32 + g * 8 + half * 4;
        if (d < HD) {
          __align__(8) bf16 w[4] = {f2b(oacc[dt][g * 4 + 0] * inv),
                                    f2b(oacc[dt][g * 4 + 1] * inv),
                                    f2b(oacc[dt][g * 4 + 2] * inv),
                                    f2b(oacc[dt][g * 4 + 3] * inv)};
          *reinterpret_cast<uint2*>(op + d) = *reinterpret_cast<const uint2*>(w);
        }
      }
    }
  }
}

// ---------------------------------------------------------------------------
extern "C" void kernel_launch(void* const* d_in, const int* in_sizes, int n_in,
                              void* d_out, int out_size, void* d_ws, size_t ws_size,
                              hipStream_t stream) {
  const float* hs    = (const float*)d_in[0];
  const int*   cu    = (const int*)d_in[1];
  const float* cosb  = (const float*)d_in[2];
  const float* sinb  = (const float*)d_in[3];
  const float* Wqkv  = (const float*)d_in[4];
  const float* bqkv  = (const float*)d_in[5];
  const float* Wproj = (const float*)d_in[6];
  const float* bproj = (const float*)d_in[7];

  // ws: qkv bf16 15.73MB | attn_out bf16 5.24MB | WqkvT 9.83MB | WprojT 3.28MB
  //     | hs_bf16 5.24MB  = 39.3 MB
  bf16* qkv      = (bf16*)d_ws;
  bf16* attn_out = qkv + (size_t)N_TOK * QKV_N;
  bf16* WqkvT    = attn_out + (size_t)N_TOK * DIM;
  bf16* WprojT   = WqkvT + (size_t)QKV_N * DIM;
  bf16* hsb      = WprojT + (size_t)DIM * DIM;

  // 0) fused prep: cast hs + transpose both weights
  prep_kernel<<<dim3(QKV_N / 32, DIM / 32, 3), 256, 0, stream>>>(
      hs, hsb, Wqkv, WqkvT, Wproj, WprojT);

  // 1) qkv = bf16(hsb @ Wqkv + bqkv)   (RAW — rope is fused into attention)
  mfma_gemm<1><<<dim3(QKV_N / 128, N_TOK / 128), 256, 0, stream>>>(
      hsb, WqkvT, bqkv, qkv, N_TOK, QKV_N, DIM);

  // 2) MFMA flash attention (rope fused) -> attn_out (bf16)
  int nseg = in_sizes[1] - 1;
  int nblk = (N_TOK / 128) * nseg * NHEAD;   // 512 for nseg=2 (divisible by 8)
  attn_mfma_kernel<<<nblk, 256, 0, stream>>>(qkv, cu, cosb, sinb, attn_out, nseg);

  // 3) out = attn_out @ Wproj + bproj (fp32 out)
  mfma_gemm<0><<<dim3(DIM / 128, N_TOK / 128), 256, 0, stream>>>(
      attn_out, WprojT, bproj, d_out, N_TOK, DIM, DIM);
}

// Round 16
// 111.918 us; speedup vs baseline: 1.1002x; 1.1002x over previous
//
#include <hip/hip_runtime.h>
#include <hip/hip_bf16.h>

// Problem constants (Qwen3.5-VL vision attention)
constexpr int N_TOK  = 2048;
constexpr int DIM    = 1280;
constexpr int NHEAD  = 16;
constexpr int HD     = 80;
constexpr int QKV_N  = 3 * DIM;   // 3840

using bf16 = __hip_bfloat16;
typedef __attribute__((ext_vector_type(4)))  float f32x4;
typedef __attribute__((ext_vector_type(16))) float f32x16;
typedef __attribute__((ext_vector_type(8)))  short short8;  // 8 bf16 = 4 VGPR
typedef unsigned int uint;

__device__ __forceinline__ float b2f(bf16 x) { return __bfloat162float(x); }
__device__ __forceinline__ bf16  f2b(float x) { return __float2bfloat16(x); }

// pack two floats -> one u32 of 2 bf16 (lo = first)
__device__ __forceinline__ uint pk2(float a, float b) {
  __align__(4) bf16 t[2] = {f2b(a), f2b(b)};
  return *reinterpret_cast<uint*>(t);
}

// async global->LDS, 16B per lane; dest is wave-uniform base + lane*16
typedef const __attribute__((address_space(1))) unsigned int* gas_u32;
typedef __attribute__((address_space(3))) unsigned int* las_u32;
__device__ __forceinline__ void gload_lds16(const void* g, void* l) {
  __builtin_amdgcn_global_load_lds((gas_u32)g, (las_u32)l, 16, 0, 0);
}

// ---------------------------------------------------------------------------
// Fused prep: z=0 cast hs->bf16, z=1 transpose Wqkv, z=2 transpose Wproj.
// ---------------------------------------------------------------------------
__device__ __forceinline__ void transpose_body(const float* __restrict__ W,
                                               bf16* __restrict__ WT, int K, int N) {
  __shared__ float tile[32][33];
  const int n0 = blockIdx.x * 32, k0 = blockIdx.y * 32;
  const int tc = threadIdx.x & 31, tr = threadIdx.x >> 5;
#pragma unroll
  for (int r = tr; r < 32; r += 8)
    tile[r][tc] = W[(size_t)(k0 + r) * N + n0 + tc];
  __syncthreads();
#pragma unroll
  for (int r = tr; r < 32; r += 8)
    WT[(size_t)(n0 + r) * K + k0 + tc] = f2b(tile[tc][r]);
}

__global__ __launch_bounds__(256)
void prep_kernel(const float* __restrict__ hs, bf16* __restrict__ hsb,
                 const float* __restrict__ Wqkv, bf16* __restrict__ WqkvT,
                 const float* __restrict__ Wproj, bf16* __restrict__ WprojT) {
  if (blockIdx.z == 0) {
    const int bid = blockIdx.y * gridDim.x + blockIdx.x;
    if (bid >= (N_TOK * DIM) / 2048) return;
    const int i = bid * 2048 + threadIdx.x * 8;
    const float4 a = *reinterpret_cast<const float4*>(hs + i);
    const float4 b = *reinterpret_cast<const float4*>(hs + i + 4);
    __align__(16) bf16 w[8] = {f2b(a.x), f2b(a.y), f2b(a.z), f2b(a.w),
                               f2b(b.x), f2b(b.y), f2b(b.z), f2b(b.w)};
    *reinterpret_cast<short8*>(hsb + i) = *reinterpret_cast<const short8*>(w);
  } else if (blockIdx.z == 1) {
    transpose_body(Wqkv, WqkvT, DIM, QKV_N);           // grid (120,40)
  } else {
    if (blockIdx.x >= DIM / 32) return;
    transpose_body(Wproj, WprojT, DIM, DIM);           // (40,40)
  }
}

// ---------------------------------------------------------------------------
// m97-style MFMA GEMM (R7-verified): C = A(bf16) @ BT(bf16) + bias(fp32)
// BM=BN=128, BK=64, 4 waves, global_load_lds w16 + pre-swizzled source.
// ---------------------------------------------------------------------------
template <int OBF>  // 1: C bf16, 0: C fp32
__global__ __launch_bounds__(256)
void mfma_gemm(const bf16* __restrict__ A, const bf16* __restrict__ BT,
               const float* __restrict__ bias, void* __restrict__ C,
               int M, int N, int K) {
  __shared__ bf16 As[128 * 64];
  __shared__ bf16 Bs[128 * 64];
  const int tid = threadIdx.x;
  const int wid = tid >> 6, lane = tid & 63;
  const int lm = lane & 15, kg = lane >> 4;
  const int wm = (wid >> 1) * 64, wn = (wid & 1) * 64;
  const int m0 = blockIdx.y * 128, n0 = blockIdx.x * 128;

  const int srow = lane >> 3;
  const int sblk = (lane & 7) ^ srow;

  f32x4 acc[4][4];
#pragma unroll
  for (int i = 0; i < 4; ++i)
#pragma unroll
    for (int j = 0; j < 4; ++j) acc[i][j] = (f32x4){0.f, 0.f, 0.f, 0.f};

  for (int k0 = 0; k0 < K; k0 += 64) {
#pragma unroll
    for (int i = 0; i < 4; ++i) {
      const int slot = i * 4 + wid;
      const int row = slot * 8 + srow;
      gload_lds16(A + (size_t)(m0 + row) * K + k0 + sblk * 8, &As[slot * 512]);
      gload_lds16(BT + (size_t)(n0 + row) * K + k0 + sblk * 8, &Bs[slot * 512]);
    }
    __syncthreads();

#pragma unroll
    for (int kh = 0; kh < 2; ++kh) {
      short8 af[4], bfr[4];
#pragma unroll
      for (int t = 0; t < 4; ++t) {
        const int ar = wm + t * 16 + lm;
        af[t] = *reinterpret_cast<const short8*>(
            &As[ar * 64 + ((kh * 4 + kg) ^ (ar & 7)) * 8]);
        const int br = wn + t * 16 + lm;
        bfr[t] = *reinterpret_cast<const short8*>(
            &Bs[br * 64 + ((kh * 4 + kg) ^ (br & 7)) * 8]);
      }
#pragma unroll
      for (int mi = 0; mi < 4; ++mi)
#pragma unroll
        for (int ni = 0; ni < 4; ++ni)
          acc[mi][ni] = __builtin_amdgcn_mfma_f32_16x16x32_bf16(
              af[mi], bfr[ni], acc[mi][ni], 0, 0, 0);
    }
    __syncthreads();
  }

#pragma unroll
  for (int mi = 0; mi < 4; ++mi) {
#pragma unroll
    for (int ni = 0; ni < 4; ++ni) {
      const int col = n0 + wn + ni * 16 + lm;
      const float bv = bias[col];
#pragma unroll
      for (int r = 0; r < 4; ++r) {
        const int row = m0 + wm + mi * 16 + kg * 4 + r;
        const float v = acc[mi][ni][r] + bv;
        if constexpr (OBF)
          ((bf16*)C)[(size_t)row * N + col] = f2b(v);
        else
          ((float*)C)[(size_t)row * N + col] = v;
      }
    }
  }
}

// ---------------------------------------------------------------------------
// RoPE, K-ONLY (Q-rope is fused into attention). Vectorized, 8 pairs/thread.
// ---------------------------------------------------------------------------
__global__ __launch_bounds__(256)
void rope_k_kernel(bf16* __restrict__ qkv, const float* __restrict__ cosb,
                   const float* __restrict__ sinb) {
  const int idx = blockIdx.x * 256 + threadIdx.x;   // over N*H*5
  const int d0  = (idx % 5) * 8;
  const int h   = (idx / 5) % NHEAD;
  const int n   = idx / (5 * NHEAD);
  const size_t base = (size_t)n * QKV_N + DIM + h * HD;

  short8 a = *reinterpret_cast<const short8*>(qkv + base + d0);        // x1
  short8 b = *reinterpret_cast<const short8*>(qkv + base + 40 + d0);   // x2
  float cc1[8], cc2[8], ss1[8], ss2[8];
  *reinterpret_cast<float4*>(&cc1[0]) = *reinterpret_cast<const float4*>(cosb + n * HD + d0);
  *reinterpret_cast<float4*>(&cc1[4]) = *reinterpret_cast<const float4*>(cosb + n * HD + d0 + 4);
  *reinterpret_cast<float4*>(&cc2[0]) = *reinterpret_cast<const float4*>(cosb + n * HD + 40 + d0);
  *reinterpret_cast<float4*>(&cc2[4]) = *reinterpret_cast<const float4*>(cosb + n * HD + 44 + d0);
  *reinterpret_cast<float4*>(&ss1[0]) = *reinterpret_cast<const float4*>(sinb + n * HD + d0);
  *reinterpret_cast<float4*>(&ss1[4]) = *reinterpret_cast<const float4*>(sinb + n * HD + d0 + 4);
  *reinterpret_cast<float4*>(&ss2[0]) = *reinterpret_cast<const float4*>(sinb + n * HD + 40 + d0);
  *reinterpret_cast<float4*>(&ss2[4]) = *reinterpret_cast<const float4*>(sinb + n * HD + 44 + d0);

  __align__(16) bf16 o1[8], o2[8];
#pragma unroll
  for (int e = 0; e < 8; ++e) {
    const float x1 = b2f(reinterpret_cast<const bf16*>(&a)[e]);
    const float x2 = b2f(reinterpret_cast<const bf16*>(&b)[e]);
    o1[e] = f2b(x1 * cc1[e] - x2 * ss1[e]);
    o2[e] = f2b(x2 * cc2[e] + x1 * ss2[e]);
  }
  *reinterpret_cast<short8*>(qkv + base + d0)      = *reinterpret_cast<const short8*>(o1);
  *reinterpret_cast<short8*>(qkv + base + 40 + d0) = *reinterpret_cast<const short8*>(o2);
}

// ---------------------------------------------------------------------------
// MFMA flash attention, R16 = R14 chunk loop (raw K/V staging, dbuf K + dbuf
// Vt, ONE barrier/chunk, lazy softmax, in-register P via permlane32_swap,
// XCD remap) + Q-rope fused in the prologue (R15-verified permlane mapping).
// ---------------------------------------------------------------------------
constexpr int KC   = 64;   // keys per chunk
constexpr int KSTR = 104;  // 208B rows (pads 80..103 never read by 32x32 path)
constexpr int VSTR = 88;   // 176B rows; key XOR swizzle, 16B-aligned reads
constexpr int VROWS = 96;  // 80 real d + 16 zero rows for the dt=2 tile

__global__ __launch_bounds__(256)
void attn_mfma_kernel(const bf16* __restrict__ qkv, const int* __restrict__ cu,
                      const float* __restrict__ cosb, const float* __restrict__ sinb,
                      bf16* __restrict__ out, int nseg) {
  __shared__ bf16 Ks[2][KC * KSTR];      // 26624 B [key][d] (K pre-roped)
  __shared__ bf16 Vt[2][VROWS * VSTR];   // 33792 B [d][key^swz], rows 80+ = 0

  // XCD-aware remap (bijective: gridDim.x % 8 == 0)
  const int p = blockIdx.x;
  const int lidx = (p & 7) * (gridDim.x >> 3) + (p >> 3);
  const int xt  = lidx & 15;             // q-tile (N_TOK/128 = 16)
  const int seg = (lidx >> 4) % nseg;
  const int h   = (lidx >> 4) / nseg;

  const int s0 = cu[seg], s1 = cu[seg + 1];
  if (s0 + xt * 128 >= s1) return;  // uniform early-exit

  const int tid  = threadIdx.x;
  const int wid  = tid >> 6, lane = tid & 63;
  const int l31  = lane & 31;
  const int half = lane >> 5;            // 0/1: which 32-lane half
  const float scale = 0.11180339887498949f;  // 80^-0.5

  const int qrow = s0 + xt * 128 + wid * 32 + l31;

  // zero-fill Vt rows 80..95 in BOTH buffers (2 x 176 slots)
#pragma unroll
  for (int t = 0; t < 2; ++t) {
    const int s = tid + t * 256;
    if (s < 352) {
      const int b = s / 176, rem = s % 176;
      const int r = 80 + rem / 11, sl = rem % 11;
      *reinterpret_cast<short8*>(&Vt[b][r * VSTR + sl * 8]) =
          (short8){0, 0, 0, 0, 0, 0, 0, 0};
    }
  }

  // ---- Q load (raw) + in-register RoPE (R15-verified permlane mapping) ----
  short8 qraw[5];
  const int nclamp = min(qrow, s1 - 1);
#pragma unroll
  for (int j = 0; j < 5; ++j) {
    const int dbase = j * 16 + half * 8;
    qraw[j] = (qrow < s1)
        ? *reinterpret_cast<const short8*>(qkv + (size_t)qrow * QKV_N + h * HD + dbase)
        : (short8){0, 0, 0, 0, 0, 0, 0, 0};
  }
  short8 part[5];
#pragma unroll
  for (int w = 0; w < 4; ++w) {
    const uint d0 = reinterpret_cast<const uint*>(&qraw[0])[w];
    const uint d1 = reinterpret_cast<const uint*>(&qraw[1])[w];
    const uint d2 = reinterpret_cast<const uint*>(&qraw[2])[w];
    const uint d3 = reinterpret_cast<const uint*>(&qraw[3])[w];
    const uint d4 = reinterpret_cast<const uint*>(&qraw[4])[w];
    auto s1p = __builtin_amdgcn_permlane32_swap(d2, d0, false, false);
    auto s2p = __builtin_amdgcn_permlane32_swap(d4, d2, false, false);
    auto s3p = __builtin_amdgcn_permlane32_swap(d0, d3, false, false);
    auto s4p = __builtin_amdgcn_permlane32_swap(d3, d1, false, false);
    auto s5p = __builtin_amdgcn_permlane32_swap(d1, d4, false, false);
    reinterpret_cast<uint*>(&part[0])[w] = half ? s3p[0] : s1p[1];
    reinterpret_cast<uint*>(&part[1])[w] = half ? s5p[0] : s4p[1];
    reinterpret_cast<uint*>(&part[2])[w] = half ? s1p[0] : s2p[1];
    reinterpret_cast<uint*>(&part[3])[w] = half ? s4p[0] : s3p[1];
    reinterpret_cast<uint*>(&part[4])[w] = half ? s2p[0] : s5p[1];
  }
  short8 qa[5];
  {
    const float* cq = cosb + nclamp * HD;
    const float* sq = sinb + nclamp * HD;
#pragma unroll
    for (int j = 0; j < 5; ++j) {
      const int dbase = j * 16 + half * 8;
      float cv[8], sv[8];
      *reinterpret_cast<float4*>(&cv[0]) = *reinterpret_cast<const float4*>(cq + dbase);
      *reinterpret_cast<float4*>(&cv[4]) = *reinterpret_cast<const float4*>(cq + dbase + 4);
      *reinterpret_cast<float4*>(&sv[0]) = *reinterpret_cast<const float4*>(sq + dbase);
      *reinterpret_cast<float4*>(&sv[4]) = *reinterpret_cast<const float4*>(sq + dbase + 4);
      const float sgn = (dbase < 40) ? -1.f : 1.f;
      __align__(16) bf16 o[8];
#pragma unroll
      for (int e = 0; e < 8; ++e) {
        const float x  = b2f(reinterpret_cast<const bf16*>(&qraw[j])[e]);
        const float xp = b2f(reinterpret_cast<const bf16*>(&part[j])[e]);
        o[e] = f2b(x * cv[e] + sgn * xp * sv[e]);
      }
      qa[j] = *reinterpret_cast<const short8*>(o);
    }
  }

  // ---- staging lambdas (R14: raw K, raw V; K was roped by rope_k_kernel) ----
  short8 kreg[3], vreg[4];
  const int vgrp = tid / 10, vsl = tid % 10;  // valid for tid<160
  auto issueK = [&](int c) {
    const int k0 = s0 + c * KC;
#pragma unroll
    for (int t = 0; t < 3; ++t) {
      const int s = tid + t * 256;
      if (s < 640) {
        const int r = min(k0 + s / 10, s1 - 1);
        kreg[t] = *reinterpret_cast<const short8*>(
            qkv + (size_t)r * QKV_N + DIM + h * HD + (s % 10) * 8);
      }
    }
  };
  auto commitK = [&](int buf) {
#pragma unroll
    for (int t = 0; t < 3; ++t) {
      const int s = tid + t * 256;
      if (s < 640)
        *reinterpret_cast<short8*>(&Ks[buf][(s / 10) * KSTR + (s % 10) * 8]) =
            kreg[t];
    }
  };
  auto issueV = [&](int c) {
    if (tid < 160) {
      const int k0 = s0 + c * KC;
#pragma unroll
      for (int e = 0; e < 4; ++e) {
        const int r = min(k0 + vgrp * 4 + e, s1 - 1);
        vreg[e] = *reinterpret_cast<const short8*>(
            qkv + (size_t)r * QKV_N + 2 * DIM + h * HD + vsl * 8);
      }
    }
  };
  auto commitV = [&](int buf) {
    if (tid < 160) {
      const int r0 = vgrp * 4;
      const int swz = (vsl & 7) << 3;
#pragma unroll
      for (int de = 0; de < 8; ++de) {
        __align__(8) bf16 w[4] = {reinterpret_cast<const bf16*>(&vreg[0])[de],
                                  reinterpret_cast<const bf16*>(&vreg[1])[de],
                                  reinterpret_cast<const bf16*>(&vreg[2])[de],
                                  reinterpret_cast<const bf16*>(&vreg[3])[de]};
        *reinterpret_cast<uint2*>(&Vt[buf][(vsl * 8 + de) * VSTR + (r0 ^ swz)]) =
            *reinterpret_cast<const uint2*>(w);
      }
    }
  };

  f32x16 oacc[3];
#pragma unroll
  for (int dt = 0; dt < 3; ++dt)
#pragma unroll
    for (int r = 0; r < 16; ++r) oacc[dt][r] = 0.f;
  float m = -1e30f, l = 0.f;   // per-lane; q's data lives in lanes q, q+32
  const int nch = (s1 - s0 + KC - 1) / KC;

  issueK(0);
  issueV(0);
  commitK(0);
  commitV(0);
  if (nch > 1) {
    issueK(1);
    issueV(1);
  }
  __syncthreads();

  for (int c = 0; c < nch; ++c) {
    const int cur = c & 1;
    const int nk = min(KC, s1 - (s0 + c * KC));

    // 1. S^T = K . Q^T : 2 key-tiles x 5 d-chunks (32x32x16)
    f32x16 sc[2];
    __builtin_amdgcn_s_setprio(1);
#pragma unroll
    for (int kt = 0; kt < 2; ++kt) {
#pragma unroll
      for (int r = 0; r < 16; ++r) sc[kt][r] = 0.f;
#pragma unroll
      for (int ck = 0; ck < 5; ++ck) {
        short8 ka = *reinterpret_cast<const short8*>(
            &Ks[cur][(kt * 32 + l31) * KSTR + ck * 16 + half * 8]);
        sc[kt] = __builtin_amdgcn_mfma_f32_32x32x16_bf16(ka, qa[ck], sc[kt], 0, 0, 0);
      }
    }
    __builtin_amdgcn_s_setprio(0);

    // 2. pipeline: commit K/V(c+1) into buf^1, issue K/V(c+2)
    if (c + 1 < nch) {
      commitK(cur ^ 1);
      commitV(cur ^ 1);
    }
    if (c + 2 < nch) {
      issueK(c + 2);
      issueV(c + 2);
    }

    // 3. scale, tail-mask, LAZY online softmax
#pragma unroll
    for (int kt = 0; kt < 2; ++kt)
#pragma unroll
      for (int r = 0; r < 16; ++r) sc[kt][r] *= scale;
    if (nk < KC) {
#pragma unroll
      for (int kt = 0; kt < 2; ++kt)
#pragma unroll
        for (int r = 0; r < 16; ++r) {
          const int key = kt * 32 + (r & 3) + 8 * (r >> 2) + 4 * half;
          if (key >= nk) sc[kt][r] = -1e30f;
        }
    }
    float rml = sc[0][0];
#pragma unroll
    for (int kt = 0; kt < 2; ++kt)
#pragma unroll
      for (int r = 0; r < 16; ++r)
        if (kt | r) rml = fmaxf(rml, sc[kt][r]);
    if (!__all(rml - m <= 8.0f)) {   // rare: real max growth -> full reduce
      float rm = fmaxf(rml, __shfl_xor(rml, 32));
      const float mnew = fmaxf(m, rm);
      const float fs = __expf(m - mnew);
      m = mnew;
      l *= fs;
#pragma unroll
      for (int dt = 0; dt < 3; ++dt)
#pragma unroll
        for (int r = 0; r < 16; ++r) oacc[dt][r] *= fs;
    }
    // exp in place; per-lane partial l (P bounded by e^8)
#pragma unroll
    for (int kt = 0; kt < 2; ++kt)
#pragma unroll
      for (int r = 0; r < 16; ++r) {
        sc[kt][r] = __expf(sc[kt][r] - m);
        l += sc[kt][r];
      }

    // 4. P -> bf16 words -> permlane32_swap assembly of PV B-frags.
    uint pbw[4][4];  // [kchunk = kt*2+kc2][word 0..3]
#pragma unroll
    for (int kt = 0; kt < 2; ++kt) {
      uint w[8];
#pragma unroll
      for (int i = 0; i < 8; ++i) w[i] = pk2(sc[kt][2 * i], sc[kt][2 * i + 1]);
#pragma unroll
      for (int kc2 = 0; kc2 < 2; ++kc2) {
        auto r02 = __builtin_amdgcn_permlane32_swap(w[4 * kc2 + 0],
                                                    w[4 * kc2 + 2], false, false);
        auto r13 = __builtin_amdgcn_permlane32_swap(w[4 * kc2 + 1],
                                                    w[4 * kc2 + 3], false, false);
        pbw[kt * 2 + kc2][0] = r02[0];
        pbw[kt * 2 + kc2][1] = r13[0];
        pbw[kt * 2 + kc2][2] = r02[1];
        pbw[kt * 2 + kc2][3] = r13[1];
      }
    }

    // 5. O^T += V^T . P^T : 4 key-chunks x 3 d-tiles (32x32x16)
    __builtin_amdgcn_s_setprio(1);
#pragma unroll
    for (int kc = 0; kc < 4; ++kc) {
      short8 pb = *reinterpret_cast<const short8*>(&pbw[kc][0]);
#pragma unroll
      for (int dt = 0; dt < 3; ++dt) {
        const int d = dt * 32 + l31;
        short8 va = *reinterpret_cast<const short8*>(
            &Vt[cur][d * VSTR + ((kc * 16 + half * 8) ^ (((d >> 3) & 7) << 3))]);
        oacc[dt] = __builtin_amdgcn_mfma_f32_32x32x16_bf16(va, pb, oacc[dt], 0, 0, 0);
      }
    }
    __builtin_amdgcn_s_setprio(0);

    __syncthreads();  // single barrier: seals buf^1 writes, frees buf[cur]
  }

  // ---- epilogue: l across halves; D row = (reg&3)+8*(reg>>2)+4*half ----
  l += __shfl_xor(l, 32);
  if (qrow < s1) {
    const float inv = 1.f / l;
    bf16* op = out + (size_t)qrow * DIM + h * HD;
#pragma unroll
    for (int dt = 0; dt < 3; ++dt) {
#pragma unroll
      for (int g = 0; g < 4; ++g) {
        const int d = dt * 32 + g * 8 + half * 4;
        if (d < HD) {
          __align__(8) bf16 w[4] = {f2b(oacc[dt][g * 4 + 0] * inv),
                                    f2b(oacc[dt][g * 4 + 1] * inv),
                                    f2b(oacc[dt][g * 4 + 2] * inv),
                                    f2b(oacc[dt][g * 4 + 3] * inv)};
          *reinterpret_cast<uint2*>(op + d) = *reinterpret_cast<const uint2*>(w);
        }
      }
    }
  }
}

// ---------------------------------------------------------------------------
extern "C" void kernel_launch(void* const* d_in, const int* in_sizes, int n_in,
                              void* d_out, int out_size, void* d_ws, size_t ws_size,
                              hipStream_t stream) {
  const float* hs    = (const float*)d_in[0];
  const int*   cu    = (const int*)d_in[1];
  const float* cosb  = (const float*)d_in[2];
  const float* sinb  = (const float*)d_in[3];
  const float* Wqkv  = (const float*)d_in[4];
  const float* bqkv  = (const float*)d_in[5];
  const float* Wproj = (const float*)d_in[6];
  const float* bproj = (const float*)d_in[7];

  // ws: qkv bf16 15.73MB | attn_out bf16 5.24MB | WqkvT 9.83MB | WprojT 3.28MB
  //     | hs_bf16 5.24MB  = 39.3 MB
  bf16* qkv      = (bf16*)d_ws;
  bf16* attn_out = qkv + (size_t)N_TOK * QKV_N;
  bf16* WqkvT    = attn_out + (size_t)N_TOK * DIM;
  bf16* WprojT   = WqkvT + (size_t)QKV_N * DIM;
  bf16* hsb      = WprojT + (size_t)DIM * DIM;

  // 0) fused prep: cast hs + transpose both weights
  prep_kernel<<<dim3(QKV_N / 32, DIM / 32, 3), 256, 0, stream>>>(
      hs, hsb, Wqkv, WqkvT, Wproj, WprojT);

  // 1) qkv = bf16(hsb @ Wqkv + bqkv)
  mfma_gemm<1><<<dim3(QKV_N / 128, N_TOK / 128), 256, 0, stream>>>(
      hsb, WqkvT, bqkv, qkv, N_TOK, QKV_N, DIM);

  // 2) RoPE on K only (Q-rope fused into attention)
  rope_k_kernel<<<(N_TOK * NHEAD * 5) / 256, 256, 0, stream>>>(qkv, cosb, sinb);

  // 3) MFMA flash attention (Q-rope fused) -> attn_out (bf16)
  int nseg = in_sizes[1] - 1;
  int nblk = (N_TOK / 128) * nseg * NHEAD;   // 512 for nseg=2 (divisible by 8)
  attn_mfma_kernel<<<nblk, 256, 0, stream>>>(qkv, cu, cosb, sinb, attn_out, nseg);

  // 4) out = attn_out @ Wproj + bproj (fp32 out)
  mfma_gemm<0><<<dim3(DIM / 128, N_TOK / 128), 256, 0, stream>>>(
      attn_out, WprojT, bproj, d_out, N_TOK, DIM, DIM);
}